// Round 6
// baseline (1151.393 us; speedup 1.0000x reference)
//
#include <hip/hip_runtime.h>
#include <hip/hip_bf16.h>
#include <math.h>

#define L_SEQ 6464
#define DM 64
#define DI 128
#define DS 16
#define CHUNK 64
#define NCH 101   // 6464 = 101 * 64; chunk starts are 16B-aligned

// ---------------- prologue: concat + pos, then @W_fcc + b_fcc ----------------
__global__ void k_embed(const float* __restrict__ DNA, const float* __restrict__ CpG,
                        const float* __restrict__ cell, const float* __restrict__ pos,
                        const float* __restrict__ Wfcc, const float* __restrict__ bfcc,
                        float* __restrict__ x0) {
    int l = blockIdx.x;
    int j = threadIdx.x;  // 64
    __shared__ float in64[64];
    float v;
    if (j < 16)       v = CpG[l * 16 + j];
    else if (j < 32)  v = cell[l * 16 + (j - 16)];
    else              v = DNA[l * 32 + (j - 32)];
    v += pos[l * 64 + j];
    in64[j] = v;
    __syncthreads();
    float acc = bfcc[j];
    for (int i = 0; i < 64; i++) acc += in64[i] * Wfcc[i * 64 + j];
    x0[(size_t)l * 64 + j] = acc;
}

// ---------------- xz = x @ W_in : 8 rows/block, f4 LDS reads ----------------
__global__ void __launch_bounds__(256) k_gemm_in(const float* __restrict__ x,
                                                 const float* __restrict__ Win,
                                                 float* __restrict__ xz) {
    __shared__ __align__(16) float s_x[8][64];
    int t0 = blockIdx.x * 8;
    int tid = threadIdx.x;
    for (int i = tid; i < 8 * 64; i += 256) {
        int rr = i >> 6, c = i & 63;
        s_x[rr][c] = x[(size_t)(t0 + rr) * 64 + c];
    }
    __syncthreads();
    int j = tid;  // 256 cols
    float acc[8];
    #pragma unroll
    for (int r = 0; r < 8; r++) acc[r] = 0.f;
    for (int i = 0; i < 64; i += 4) {
        float w0 = Win[(i + 0) * 256 + j];
        float w1 = Win[(i + 1) * 256 + j];
        float w2 = Win[(i + 2) * 256 + j];
        float w3 = Win[(i + 3) * 256 + j];
        #pragma unroll
        for (int r = 0; r < 8; r++) {
            float4 xv = *(const float4*)&s_x[r][i];
            acc[r] = fmaf(xv.x, w0, fmaf(xv.y, w1, fmaf(xv.z, w2, fmaf(xv.w, w3, acc[r]))));
        }
    }
    #pragma unroll
    for (int r = 0; r < 8; r++) xz[(size_t)(t0 + r) * 256 + j] = acc[r];
}

// ------- fused conv(+silu) both dirs + xdbl + dt/B/C -> TRANSPOSED outputs -------
__global__ void __launch_bounds__(256) k_convdt(
        const float* __restrict__ xz, const float* __restrict__ convw,
        const float* __restrict__ convb, const float* __restrict__ Wxp,
        const float* __restrict__ Wdt, const float* __restrict__ bdt,
        float* __restrict__ dtT, float* __restrict__ xcT,
        float* __restrict__ BT, float* __restrict__ CT) {
    __shared__ __align__(16) float s_xi[22][128];    // xi rows t0-3 .. t0+18
    __shared__ __align__(16) float s_xc[16][128];
    __shared__ __align__(16) float s_dtl[16][128];
    __shared__ __align__(16) float s_xd[16][36];
    __shared__ __align__(16) float s_wxpT[36 * 132]; // wxpT[t][i], stride 132 (16B-aligned)
    int t0 = blockIdx.x * 16;
    int tid = threadIdx.x;
    for (int i = tid; i < 128 * 36; i += 256) {
        int ii = i / 36, t = i - ii * 36;
        s_wxpT[t * 132 + ii] = Wxp[i];
    }
    for (int i = tid; i < 22 * 32; i += 256) {
        int rr = i >> 5, q = i & 31;
        int r = t0 - 3 + rr;
        float4 v = make_float4(0.f, 0.f, 0.f, 0.f);
        if (r >= 0 && r < L_SEQ) v = *(const float4*)&xz[(size_t)r * 256 + 4 * q];
        s_xi[rr][4 * q + 0] = v.x;
        s_xi[rr][4 * q + 1] = v.y;
        s_xi[rr][4 * q + 2] = v.z;
        s_xi[rr][4 * q + 3] = v.w;
    }
    __syncthreads();
    for (int dir = 0; dir < 2; dir++) {
        // conv + silu
        for (int i = tid; i < 16 * 128; i += 256) {
            int rr = i >> 7, d = i & 127;
            int lr = rr + 3;
            float acc = convb[d];
            if (dir == 0) {
                #pragma unroll
                for (int k = 0; k < 4; k++) acc += convw[d * 4 + k] * s_xi[lr - 3 + k][d];
            } else {
                #pragma unroll
                for (int k = 0; k < 4; k++) acc += convw[d * 4 + k] * s_xi[lr + 3 - k][d];
            }
            s_xc[rr][d] = acc / (1.f + expf(-acc));
        }
        __syncthreads();
        // xdbl = xc @ W_xp (36 cols), b128 both operands
        for (int o = tid; o < 16 * 36; o += 256) {
            int rr = o / 36, t = o - rr * 36;
            float acc = 0.f;
            for (int i = 0; i < 128; i += 4) {
                float4 xv = *(const float4*)&s_xc[rr][i];
                float4 wv = *(const float4*)&s_wxpT[t * 132 + i];
                acc += xv.x * wv.x + xv.y * wv.y + xv.z * wv.z + xv.w * wv.w;
            }
            s_xd[rr][t] = acc;
        }
        __syncthreads();
        // dt = softplus(xdbl[:, :4] @ W_dt + b_dt)
        for (int o = tid; o < 16 * 128; o += 256) {
            int rr = o >> 7, d = o & 127;
            float pre = bdt[d];
            #pragma unroll
            for (int r = 0; r < 4; r++) pre += s_xd[rr][r] * Wdt[r * 128 + d];
            s_dtl[rr][d] = (pre > 20.f) ? pre : log1pf(expf(pre));
        }
        __syncthreads();
        // transposed stores: dtT/xcT [dir][d][L]
        for (int i = tid; i < 512; i += 256) {
            int q = i >> 7, d = i & 127;
            float4 a, b;
            a.x = s_dtl[4 * q + 0][d]; a.y = s_dtl[4 * q + 1][d];
            a.z = s_dtl[4 * q + 2][d]; a.w = s_dtl[4 * q + 3][d];
            b.x = s_xc[4 * q + 0][d];  b.y = s_xc[4 * q + 1][d];
            b.z = s_xc[4 * q + 2][d];  b.w = s_xc[4 * q + 3][d];
            size_t base = (size_t)(dir * 128 + d) * L_SEQ + t0 + 4 * q;
            *(float4*)&dtT[base] = a;
            *(float4*)&xcT[base] = b;
        }
        // BT/CT [dir][s][L]
        if (tid < 128) {
            int cc = tid >> 2, q = tid & 3;
            float4 v;
            v.x = s_xd[4 * q + 0][4 + cc]; v.y = s_xd[4 * q + 1][4 + cc];
            v.z = s_xd[4 * q + 2][4 + cc]; v.w = s_xd[4 * q + 3][4 + cc];
            float* dst = (cc < 16) ? BT : CT;
            *(float4*)&dst[(size_t)(dir * 16 + (cc & 15)) * L_SEQ + t0 + 4 * q] = v;
        }
        __syncthreads();
    }
}

// ---------------- DPP 16-lane row rotate ----------------
template<int CTRL>
__device__ __forceinline__ float ror16f(float v) {
    return __int_as_float(__builtin_amdgcn_update_dpp(0, __float_as_int(v), CTRL, 0xf, 0xf, true));
}

// ---------------- scan pass 1: register scan from transposed tensors ----------------
__global__ void __launch_bounds__(256) k_scan1s(
        const float* __restrict__ dtT, const float* __restrict__ xcT,
        const float* __restrict__ BT, const float* __restrict__ Alog,
        float* __restrict__ cA, float* __restrict__ cB) {
    int bxd = blockIdx.x;   // d-group (8)
    int c   = blockIdx.y;   // chunk (101)
    int dir = blockIdx.z;   // 2
    int tid = threadIdx.x;
    int s = tid & 15, dl = tid >> 4;
    int d = bxd * 16 + dl;
    const float* dp = dtT + (size_t)(dir * 128 + d) * L_SEQ;
    const float* xp = xcT + (size_t)(dir * 128 + d) * L_SEQ;
    const float* bp = BT  + (size_t)(dir * 16 + s) * L_SEQ;
    float A = -expf(Alog[d * 16 + s]);
    float h = 0.f, ap = 1.f;
    if (dir == 0) {
        int base = c * 64;
        #pragma unroll 4
        for (int q = 0; q < 16; q++) {
            float4 dv = *(const float4*)&dp[base + 4 * q];
            float4 xv = *(const float4*)&xp[base + 4 * q];
            float4 bv = *(const float4*)&bp[base + 4 * q];
            float a;
            a = __expf(dv.x * A); h = fmaf(a, h, dv.x * xv.x * bv.x); ap *= a;
            a = __expf(dv.y * A); h = fmaf(a, h, dv.y * xv.y * bv.y); ap *= a;
            a = __expf(dv.z * A); h = fmaf(a, h, dv.z * xv.z * bv.z); ap *= a;
            a = __expf(dv.w * A); h = fmaf(a, h, dv.w * xv.w * bv.w); ap *= a;
        }
    } else {
        #pragma unroll 4
        for (int q = 0; q < 16; q++) {
            int off = L_SEQ - 64 * c - 4 - 4 * q;
            float4 dv = *(const float4*)&dp[off];
            float4 xv = *(const float4*)&xp[off];
            float4 bv = *(const float4*)&bp[off];
            float a;
            a = __expf(dv.w * A); h = fmaf(a, h, dv.w * xv.w * bv.w); ap *= a;
            a = __expf(dv.z * A); h = fmaf(a, h, dv.z * xv.z * bv.z); ap *= a;
            a = __expf(dv.y * A); h = fmaf(a, h, dv.y * xv.y * bv.y); ap *= a;
            a = __expf(dv.x * A); h = fmaf(a, h, dv.x * xv.x * bv.x); ap *= a;
        }
    }
    size_t o = ((size_t)(dir * NCH + c) << 11) + (size_t)bxd * 256 + tid;
    cA[o] = ap;
    cB[o] = h;
}

// ------- scan pass 2: lookback + register replay; y out via small LDS transpose -------
__global__ void __launch_bounds__(256) k_scan3s(
        const float* __restrict__ dtT, const float* __restrict__ xcT,
        const float* __restrict__ BT, const float* __restrict__ CT,
        const float* __restrict__ Alog, const float* __restrict__ Dres,
        const float* __restrict__ cA, const float* __restrict__ cB,
        float* __restrict__ y) {
    __shared__ __align__(16) float s_y[16 * 80];   // [dl][t], stride 80 (16B-aligned)
    int bxd = blockIdx.x;
    int c   = blockIdx.y;
    int dir = blockIdx.z;
    int tid = threadIdx.x;
    int s = tid & 15, dl = tid >> 4;
    int d = bxd * 16 + dl;
    const float* dp = dtT + (size_t)(dir * 128 + d) * L_SEQ;
    const float* xp = xcT + (size_t)(dir * 128 + d) * L_SEQ;
    const float* bp = BT  + (size_t)(dir * 16 + s) * L_SEQ;
    const float* cp = CT  + (size_t)(dir * 16 + s) * L_SEQ;
    // lookback: fold predecessor carries (stream-ordered from k_scan1s)
    float carry = 0.f;
    int cc = 0;
    while (cc < c) {
        int n = (c - cc < 16) ? (c - cc) : 16;
        float av[16], bv[16];
        for (int j = 0; j < n; j++) {
            size_t oo = ((size_t)(dir * NCH + cc + j) << 11) + (size_t)bxd * 256 + tid;
            av[j] = cA[oo];
            bv[j] = cB[oo];
        }
        for (int j = 0; j < n; j++) carry = fmaf(av[j], carry, bv[j]);
        cc += n;
    }
    float A = -expf(Alog[d * 16 + s]);
    float Dv = Dres[d];
    float h = carry;
    if (dir == 0) {
        int base = c * 64;
        #pragma unroll 4
        for (int q = 0; q < 16; q++) {
            float4 dv = *(const float4*)&dp[base + 4 * q];
            float4 xv = *(const float4*)&xp[base + 4 * q];
            float4 bv = *(const float4*)&bp[base + 4 * q];
            float4 cv = *(const float4*)&cp[base + 4 * q];
            float a, val;
            a = __expf(dv.x * A); h = fmaf(a, h, dv.x * xv.x * bv.x);
            val = h * cv.x;
            val += ror16f<0x121>(val); val += ror16f<0x122>(val);
            val += ror16f<0x124>(val); val += ror16f<0x128>(val);
            if (s == 0) s_y[dl * 80 + 4 * q + 0] = val + xv.x * Dv;
            a = __expf(dv.y * A); h = fmaf(a, h, dv.y * xv.y * bv.y);
            val = h * cv.y;
            val += ror16f<0x121>(val); val += ror16f<0x122>(val);
            val += ror16f<0x124>(val); val += ror16f<0x128>(val);
            if (s == 0) s_y[dl * 80 + 4 * q + 1] = val + xv.y * Dv;
            a = __expf(dv.z * A); h = fmaf(a, h, dv.z * xv.z * bv.z);
            val = h * cv.z;
            val += ror16f<0x121>(val); val += ror16f<0x122>(val);
            val += ror16f<0x124>(val); val += ror16f<0x128>(val);
            if (s == 0) s_y[dl * 80 + 4 * q + 2] = val + xv.z * Dv;
            a = __expf(dv.w * A); h = fmaf(a, h, dv.w * xv.w * bv.w);
            val = h * cv.w;
            val += ror16f<0x121>(val); val += ror16f<0x122>(val);
            val += ror16f<0x124>(val); val += ror16f<0x128>(val);
            if (s == 0) s_y[dl * 80 + 4 * q + 3] = val + xv.w * Dv;
        }
    } else {
        #pragma unroll 4
        for (int q = 0; q < 16; q++) {
            int off = L_SEQ - 64 * c - 4 - 4 * q;
            float4 dv = *(const float4*)&dp[off];
            float4 xv = *(const float4*)&xp[off];
            float4 bv = *(const float4*)&bp[off];
            float4 cv = *(const float4*)&cp[off];
            float a, val;
            a = __expf(dv.w * A); h = fmaf(a, h, dv.w * xv.w * bv.w);
            val = h * cv.w;
            val += ror16f<0x121>(val); val += ror16f<0x122>(val);
            val += ror16f<0x124>(val); val += ror16f<0x128>(val);
            if (s == 0) s_y[dl * 80 + 4 * q + 0] = val + xv.w * Dv;
            a = __expf(dv.z * A); h = fmaf(a, h, dv.z * xv.z * bv.z);
            val = h * cv.z;
            val += ror16f<0x121>(val); val += ror16f<0x122>(val);
            val += ror16f<0x124>(val); val += ror16f<0x128>(val);
            if (s == 0) s_y[dl * 80 + 4 * q + 1] = val + xv.z * Dv;
            a = __expf(dv.y * A); h = fmaf(a, h, dv.y * xv.y * bv.y);
            val = h * cv.y;
            val += ror16f<0x121>(val); val += ror16f<0x122>(val);
            val += ror16f<0x124>(val); val += ror16f<0x128>(val);
            if (s == 0) s_y[dl * 80 + 4 * q + 2] = val + xv.y * Dv;
            a = __expf(dv.x * A); h = fmaf(a, h, dv.x * xv.x * bv.x);
            val = h * cv.x;
            val += ror16f<0x121>(val); val += ror16f<0x122>(val);
            val += ror16f<0x124>(val); val += ror16f<0x128>(val);
            if (s == 0) s_y[dl * 80 + 4 * q + 3] = val + xv.x * Dv;
        }
    }
    __syncthreads();
    // write y row-major: 256 items = 16 d x 16 quads
    {
        int dd = tid >> 4, q = tid & 15;
        int dg = bxd * 16 + dd;
        float4 v = *(const float4*)&s_y[dd * 80 + 4 * q];
        float* yp = y + (size_t)dir * L_SEQ * 128;
        if (dir == 0) {
            int r0 = c * 64 + 4 * q;
            yp[(size_t)(r0 + 0) * 128 + dg] = v.x;
            yp[(size_t)(r0 + 1) * 128 + dg] = v.y;
            yp[(size_t)(r0 + 2) * 128 + dg] = v.z;
            yp[(size_t)(r0 + 3) * 128 + dg] = v.w;
        } else {
            int r0 = L_SEQ - 1 - (c * 64 + 4 * q);
            yp[(size_t)(r0 - 0) * 128 + dg] = v.x;
            yp[(size_t)(r0 - 1) * 128 + dg] = v.y;
            yp[(size_t)(r0 - 2) * 128 + dg] = v.z;
            yp[(size_t)(r0 - 3) * 128 + dg] = v.w;
        }
    }
}

// ------- out-GEMM + silu(z) gate + residual + layernorm + permute; 4 rows/block -------
__global__ void __launch_bounds__(256) k_outln(
        const float* __restrict__ x, const float* __restrict__ y,
        const float* __restrict__ xz, const float* __restrict__ Wout,
        const float* __restrict__ lng, const float* __restrict__ lnb,
        float* __restrict__ xnext, int permMode) {
    __shared__ __align__(16) float s_g[4][128];
    int w = threadIdx.x >> 6;
    int j = threadIdx.x & 63;
    int l = blockIdx.x * 4 + w;
    float z1 = xz[(size_t)l * 256 + 128 + j];
    float z2 = xz[(size_t)l * 256 + 192 + j];
    float sz1 = z1 / (1.f + expf(-z1));
    float sz2 = z2 / (1.f + expf(-z2));
    s_g[w][j]      = 0.5f * (y[(size_t)l * 128 + j] + y[(size_t)(L_SEQ + l) * 128 + j]) * sz1;
    s_g[w][j + 64] = 0.5f * (y[(size_t)l * 128 + 64 + j] + y[(size_t)(L_SEQ + l) * 128 + 64 + j]) * sz2;
    __syncthreads();
    float acc = x[(size_t)l * 64 + j];
    for (int i = 0; i < 128; i += 4) {
        float4 gv = *(const float4*)&s_g[w][i];
        acc = fmaf(gv.x, Wout[(i + 0) * 64 + j], acc);
        acc = fmaf(gv.y, Wout[(i + 1) * 64 + j], acc);
        acc = fmaf(gv.z, Wout[(i + 2) * 64 + j], acc);
        acc = fmaf(gv.w, Wout[(i + 3) * 64 + j], acc);
    }
    float m = acc;
    for (int o = 32; o >= 1; o >>= 1) m += __shfl_xor(m, o);
    m *= (1.f / 64.f);
    float dv = acc - m;
    float v = dv * dv;
    for (int o = 32; o >= 1; o >>= 1) v += __shfl_xor(v, o);
    v *= (1.f / 64.f);
    float out = dv * rsqrtf(v + 1e-5f) * lng[j] + lnb[j];
    int l2;
    if (permMode == 0) l2 = (l % 64) * 101 + (l / 64);   // (s,c)->(c,s)
    else               l2 = (l % 101) * 64 + (l / 101);  // (c,s)->(s,c)
    xnext[(size_t)l2 * 64 + j] = out;
}

// ---------------- epilogue ----------------
__global__ void k_epilogue(const float* __restrict__ x, const float* __restrict__ Wfc,
                           const float* __restrict__ bfc, const float* __restrict__ ytrue,
                           const int* __restrict__ halfwin, const int* __restrict__ rows,
                           float* __restrict__ out) {
    int k = threadIdx.x;  // 64
    int hw = halfwin[0];
    int c = rows[k];
    const float* xr = x + ((size_t)hw * 64 + c) * 64;
    float acc = bfc[0];
    for (int i = 0; i < 64; i++) acc += xr[i] * Wfc[i];
    float s = 1.f / (1.f + expf(-acc));
    float r = 1.f - fabsf(ytrue[k] - s);
    out[k] = r;
}

extern "C" void kernel_launch(void* const* d_in, const int* in_sizes, int n_in,
                              void* d_out, int out_size, void* d_ws, size_t ws_size,
                              hipStream_t stream) {
    const float* DNA   = (const float*)d_in[0];
    const float* CpG   = (const float*)d_in[1];
    const float* cel   = (const float*)d_in[2];
    const float* pos   = (const float*)d_in[3];
    const float* ytrue = (const float*)d_in[4];
    const float* Wfcc  = (const float*)d_in[5];
    const float* bfcc  = (const float*)d_in[6];
    const float* Win   = (const float*)d_in[7];
    const float* convw = (const float*)d_in[8];
    const float* convb = (const float*)d_in[9];
    const float* Wxp   = (const float*)d_in[10];
    const float* Wdt   = (const float*)d_in[11];
    const float* bdt   = (const float*)d_in[12];
    const float* Alog  = (const float*)d_in[13];
    const float* Dres  = (const float*)d_in[14];
    const float* Wout  = (const float*)d_in[15];
    const float* lng   = (const float*)d_in[16];
    const float* lnb   = (const float*)d_in[17];
    const float* Wfc   = (const float*)d_in[18];
    const float* bfc   = (const float*)d_in[19];
    const int* halfwin = (const int*)d_in[20];
    const int* rows    = (const int*)d_in[21];

    float* ws = (float*)d_ws;
    size_t off = 0;
    float* x0  = ws + off; off += (size_t)L_SEQ * 64;
    float* x1  = ws + off; off += (size_t)L_SEQ * 64;
    float* xz  = ws + off; off += (size_t)L_SEQ * 256;
    float* dtT = ws + off; off += (size_t)2 * 128 * L_SEQ;
    float* xcT = ws + off; off += (size_t)2 * 128 * L_SEQ;
    float* BT  = ws + off; off += (size_t)2 * 16 * L_SEQ;
    float* CT  = ws + off; off += (size_t)2 * 16 * L_SEQ;
    float* y   = ws + off; off += (size_t)2 * L_SEQ * 128;
    float* cA  = ws + off; off += (size_t)2 * NCH * 2048;
    float* cB  = ws + off; off += (size_t)2 * NCH * 2048;

    k_embed<<<L_SEQ, 64, 0, stream>>>(DNA, CpG, cel, pos, Wfcc, bfcc, x0);

    float* xcur = x0;
    float* xnxt = x1;
    for (int sb = 0; sb < 8; sb++) {
        k_gemm_in<<<L_SEQ / 8, 256, 0, stream>>>(xcur, Win, xz);
        k_convdt<<<L_SEQ / 16, 256, 0, stream>>>(xz, convw, convb, Wxp, Wdt, bdt,
                                                 dtT, xcT, BT, CT);
        k_scan1s<<<dim3(8, NCH, 2), 256, 0, stream>>>(dtT, xcT, BT, Alog, cA, cB);
        k_scan3s<<<dim3(8, NCH, 2), 256, 0, stream>>>(dtT, xcT, BT, CT, Alog, Dres,
                                                      cA, cB, y);
        k_outln<<<L_SEQ / 4, 256, 0, stream>>>(xcur, y, xz, Wout, lng, lnb, xnxt,
                                               (sb % 2 == 0) ? 0 : 1);
        float* tmp = xcur; xcur = xnxt; xnxt = tmp;
    }

    k_epilogue<<<1, 64, 0, stream>>>(xcur, Wfc, bfc, ytrue, halfwin, rows, (float*)d_out);
}